// Round 25
// baseline (13884.790 us; speedup 1.0000x reference)
//
#include <hip/hip_runtime.h>
#include <math.h>

typedef unsigned int u32;
typedef unsigned long long u64;
typedef float f32x4 __attribute__((ext_vector_type(4)));

#define NDIG 2048          // 11-bit digits
#define TILE 1024          // elements per tile (pass-1 count/scatter)
#define NW 4
#define CAP 5632           // max bucket size for LDS-local sort (worst ~4700)

// ===== Bit-exact replica of XLA's f32 tanh =====
__device__ __forceinline__ float xla_tanhf(float x) {
    float xc = fminf(fmaxf(x, -9.0f), 9.0f);
    float x2 = __fmul_rn(xc, xc);
    float p = -2.76076847742355e-16f;
    p = __fadd_rn(__fmul_rn(p, x2),  2.00018790482477e-13f);
    p = __fadd_rn(__fmul_rn(p, x2), -8.60467152213735e-11f);
    p = __fadd_rn(__fmul_rn(p, x2),  5.12229709037114e-08f);
    p = __fadd_rn(__fmul_rn(p, x2),  1.48572235717979e-05f);
    p = __fadd_rn(__fmul_rn(p, x2),  6.37261928875436e-04f);
    p = __fadd_rn(__fmul_rn(p, x2),  4.89352455891786e-03f);
    p = __fmul_rn(xc, p);
    float q = 1.19825839466702e-06f;
    q = __fadd_rn(__fmul_rn(q, x2),  1.18534705686654e-04f);
    q = __fadd_rn(__fmul_rn(q, x2),  2.26843463243900e-03f);
    q = __fadd_rn(__fmul_rn(q, x2),  4.89352518554385e-03f);
    float r = p / q;                     // IEEE f32 divide
    return (fabsf(x) < 0.0004f) ? x : r;
}

// ascending u32 order of key_desc(f) == DESCENDING float order of f (bijective)
__device__ __forceinline__ u32 key_desc(float f) {
    u32 u = __float_as_uint(f);
    u = (u & 0x80000000u) ? ~u : (u | 0x80000000u);
    return ~u;
}

// prep (tanh+pack+cluster) + LDS-atomic count of MSD digit (bits [21,32)) + detect
__global__ void k_countP(const float* __restrict__ score, u64* __restrict__ pack0,
                         int* __restrict__ cluster,
                         const int* __restrict__ ei, const int* __restrict__ ntype,
                         u32* __restrict__ flags, u32* __restrict__ hist_dt,
                         int N, int nT) {
    __shared__ u32 run[NDIG];
    const int tile = blockIdx.x;
    const int tid = threadIdx.x;
    if (tile == 0 && tid < 64) {
        u64 b1 = __ballot(ei[2 * tid + 1] != 0);      // odd words 0 <=> int64 LE
        u64 b2 = __ballot(ntype[2 * tid + 1] != 0);
        if (tid == 0) { flags[0] = (b1 != 0ull) ? 1u : 0u;
                        flags[1] = (b2 != 0ull) ? 1u : 0u; }
    }
    for (int r = tid; r < NDIG; r += 256) run[r] = 0u;
    __syncthreads();
    const int base = tile * TILE;
    #pragma unroll
    for (int j = 0; j < 4; ++j) {
        int e = base + j * 256 + tid;
        if (e < N) {
            float t = xla_tanhf(score[e]);
            cluster[e] = -1;
            u32 key = key_desc(t);
            pack0[e] = ((u64)key << 32) | (u32)e;
            atomicAdd(&run[(key >> 21) & (NDIG - 1)], 1u);
        }
    }
    __syncthreads();
    for (int r = tid; r < NDIG; r += 256)
        hist_dt[(size_t)r * nT + tile] = run[r];       // digit-major
}

// reduce 256-entry chunks -> part[]   (proven)
__global__ void k_red(const u32* __restrict__ h, u32* __restrict__ part) {
    __shared__ u32 sh[256];
    int b = blockIdx.x, t = threadIdx.x;
    sh[t] = h[(size_t)b * 256 + t];
    __syncthreads();
    for (int off = 128; off > 0; off >>= 1) {
        if (t < off) sh[t] += sh[t + off];
        __syncthreads();
    }
    if (t == 0) part[b] = sh[0];
}

// per-chunk: base = sum(part[0..b)) strided, chunk exclusive scan IN PLACE (proven)
__global__ void k_scn(u32* __restrict__ h, const u32* __restrict__ part) {
    __shared__ u32 sh[256];
    __shared__ u32 base_sh;
    int b = blockIdx.x, t = threadIdx.x;
    u32 acc = 0;
    for (int j = t; j < b; j += 256) acc += part[j];
    sh[t] = acc;
    __syncthreads();
    for (int off = 128; off > 0; off >>= 1) {
        if (t < off) sh[t] += sh[t + off];
        __syncthreads();
    }
    if (t == 0) base_sh = sh[0];
    __syncthreads();
    u32 base = base_sh;
    u32 v = h[(size_t)b * 256 + t];
    sh[t] = v;
    __syncthreads();
    for (int off = 1; off < 256; off <<= 1) {
        u32 x = sh[t];
        u32 y = (t >= off) ? sh[t - off] : 0u;
        __syncthreads();
        sh[t] = x + y;
        __syncthreads();
    }
    h[(size_t)b * 256 + t] = base + sh[t] - v;   // exclusive prefix
}

// stable MSD scatter (bits [21,32)); 4 waves/block, wave-chunk stable ranks (proven)
__global__ void k_scatR(const u64* __restrict__ src, u64* __restrict__ dst,
                        const u32* __restrict__ scn, int N, int nT) {
    __shared__ u32 wcur[NW][NDIG];
    const int tile = blockIdx.x;
    const int tid = threadIdx.x;
    const int w = tid >> 6;
    const int lane = tid & 63;
    for (int r = tid; r < NW * NDIG; r += 256) ((u32*)wcur)[r] = 0u;
    __syncthreads();
    const int base = tile * TILE + w * 256;
    #pragma unroll
    for (int j = 0; j < 4; ++j) {
        int e = base + j * 64 + lane;
        if (e < N) {
            u32 key = (u32)(src[e] >> 32);
            atomicAdd(&wcur[w][(key >> 21) & (NDIG - 1)], 1u);
        }
    }
    __syncthreads();
    for (int r = tid; r < NDIG; r += 256) {
        u32 a0 = wcur[0][r], a1 = wcur[1][r], a2 = wcur[2][r];
        wcur[0][r] = 0u;
        wcur[1][r] = a0;
        wcur[2][r] = a0 + a1;
        wcur[3][r] = a0 + a1 + a2;
    }
    __syncthreads();
    #pragma unroll
    for (int j = 0; j < 4; ++j) {
        int e = base + j * 64 + lane;
        if (e < N) {
            u64 v = src[e];
            u32 key = (u32)(v >> 32);
            u32 d = (key >> 21) & (NDIG - 1);
            u64 m = __ballot(1);
            for (int b = 0; b < 11; ++b) {
                u64 bb = __ballot((d >> b) & 1);
                m &= ((d >> b) & 1) ? bb : ~bb;
            }
            u32 wrank = (u32)__popcll(m & ((1ull << lane) - 1ull));
            u32 old = wcur[w][d];
            u32 pos = scn[(size_t)d * nT + tile] + old + wrank;
            int leader = __ffsll(m) - 1;
            if (lane == leader) wcur[w][d] = old + (u32)__popcll(m);
            if (pos < (u32)N) dst[pos] = v;
        }
    }
}

// bucket-local LSD sort on bits [10,21): one block per MSD bucket, in LDS.
// Stability: load in order, wave-0 sequential ballot scatter preserves order.
__global__ void k_lsort(const u64* __restrict__ src, u64* __restrict__ dst,
                        const u32* __restrict__ scn, int N, int nT) {
    __shared__ u64 el[CAP];
    __shared__ u32 cnt[NDIG];
    __shared__ u32 sm[256];
    const int d = blockIdx.x;
    const int tid = threadIdx.x;
    const u32 lo = scn[(size_t)d * nT];
    const u32 hi = (d < NDIG - 1) ? scn[(size_t)(d + 1) * nT] : (u32)N;
    const int len = (int)(hi - lo);
    if (len <= 0) return;
    if (len <= CAP) {
        for (int i = tid; i < len; i += 256) el[i] = src[lo + i];
        for (int r = tid; r < NDIG; r += 256) cnt[r] = 0u;
        __syncthreads();
        for (int i = tid; i < len; i += 256) {
            u32 d2 = ((u32)(el[i] >> 32) >> 10) & (NDIG - 1);
            atomicAdd(&cnt[d2], 1u);
        }
        __syncthreads();
        // block exclusive scan of cnt[2048]: 8 per thread
        u32 s = 0;
        #pragma unroll
        for (int j = 0; j < 8; ++j) s += cnt[8 * tid + j];
        sm[tid] = s;
        __syncthreads();
        for (int off = 1; off < 256; off <<= 1) {
            u32 x = sm[tid];
            u32 y = (tid >= off) ? sm[tid - off] : 0u;
            __syncthreads();
            sm[tid] = x + y;
            __syncthreads();
        }
        u32 runv = sm[tid] - s;          // exclusive base for this thread's 8
        #pragma unroll
        for (int j = 0; j < 8; ++j) {
            u32 c = cnt[8 * tid + j];
            cnt[8 * tid + j] = runv;
            runv += c;
        }
        __syncthreads();
        // wave-0 sequential stable scatter (cursors in cnt[])
        if (tid < 64) {
            const int lane = tid;
            for (int base = 0; base < len; base += 64) {
                int e = base + lane;
                u32 d2 = 0; u64 v = 0;
                bool act = e < len;
                if (act) {
                    v = el[e];
                    d2 = ((u32)(v >> 32) >> 10) & (NDIG - 1);
                }
                u64 am = __ballot(act);
                u64 m = am;
                for (int b = 0; b < 11; ++b) {
                    u64 bb = __ballot((d2 >> b) & 1);
                    m &= ((d2 >> b) & 1) ? bb : ~bb;
                }
                if (act) {
                    u32 wrank = (u32)__popcll(m & ((1ull << lane) - 1ull));
                    u32 old = cnt[d2];
                    u32 pos = old + wrank;
                    int leader = __ffsll(m & am) - 1;
                    if (lane == leader) cnt[d2] = old + (u32)__popcll(m & am);
                    if (pos < (u32)len) dst[lo + pos] = v;
                }
            }
        }
    } else {
        // slow path (never expected): exact rank by brute force, still correct
        for (int i = tid; i < len; i += 256) {
            u64 pk = src[lo + i];
            u32 rank = 0;
            for (int j = 0; j < len; ++j) rank += (src[lo + j] < pk);
            if (rank < (u32)len) dst[lo + rank] = pk;
        }
    }
}

// fix low-10-bit/idx order within same-top22 runs (tiny) + emit perm outputs
__global__ void k_pfix(const u64* __restrict__ srt, u64* __restrict__ pay64,
                       int* __restrict__ cluster,
                       const int* __restrict__ ntype, const u32* __restrict__ ntFlag,
                       float* __restrict__ o_nt, float* __restrict__ o_perm,
                       float* __restrict__ o_vals, int k, int N) {
    int r = blockIdx.x * blockDim.x + threadIdx.x;
    if (r >= N) return;
    u64 pk = srt[r];
    u64 t22 = pk >> 42;
    int rs = r;
    while (rs > 0 && (r - rs) < 4096 && (srt[rs - 1] >> 42) == t22) --rs;
    int rf = rs;
    for (int j = rs; j < N && (j - rs) < 8192; ++j) {
        u64 q = srt[j];
        if ((q >> 42) != t22) break;
        rf += (q < pk);                  // full (key,idx) lexicographic order
    }
    if (rf < k) {
        u32 ip = (u32)pk;
        if (ip >= (u32)N) ip = 0;        // defensive
        u32 kb = (u32)(pk >> 32);
        u32 up = ~kb;                    // invert key_desc: recover tanh bits exactly
        u32 tb = (up >> 31) ? (up & 0x7FFFFFFFu) : ~up;
        pay64[rf] = ((u64)tb << 32) | ip;
        cluster[ip] = rf;
        o_perm[rf] = (float)ip;
        o_vals[rf] = __uint_as_float(tb);
        int nt = (*ntFlag == 0u) ? ntype[2 * (size_t)ip] : ntype[ip];
        o_nt[rf] = (float)nt;
    }
}

// x-gather: (val,idx) packed in pay64; regular loads, NT store
__global__ void k_gx(const u64* __restrict__ pay64,
                     const f32x4* __restrict__ x4, f32x4* __restrict__ out4,
                     int k, int Dv, int N) {
    int idx = blockIdx.x * blockDim.x + threadIdx.x;
    if (idx < k * Dv) {
        int r = idx / Dv, c = idx - r * Dv;
        u64 pv = pay64[r];
        u32 p = (u32)pv;
        float v = __uint_as_float((u32)(pv >> 32));
        if (p >= (u32)N) { p = 0; v = 0.0f; }   // defensive
        f32x4 a = x4[(size_t)p * Dv + c];
        a = a * v;
        __builtin_nontemporal_store(a, out4 + idx);
    }
}

// WAVE-chunked fused edges+attr (R16-proven)
__global__ void k_ea(const int* __restrict__ ei, const u32* __restrict__ eiFlag,
                     const float* __restrict__ elen, const int* __restrict__ cluster,
                     const f32x4* __restrict__ attr4,
                     float* __restrict__ o_ei, float* __restrict__ o_len,
                     float* __restrict__ o_mask, f32x4* __restrict__ o_attr4,
                     int E, int N) {
    const bool w64 = (*eiFlag == 0u);
    const int lane = threadIdx.x & 63;
    const int waveId = (blockIdx.x * blockDim.x + threadIdx.x) >> 6;
    const int nWaves = (gridDim.x * blockDim.x) >> 6;
    const int nChunk = (E + 63) >> 6;
    for (int ch = waveId; ch < nChunk; ch += nWaves) {
        int e = ch * 64 + lane;
        int mfl = 0;
        if (e < E) {
            int a, b;
            if (w64) { a = ei[2 * (size_t)e]; b = ei[2 * ((size_t)E + (size_t)e)]; }
            else { a = ei[e]; b = ei[(size_t)E + e]; }
            bool ok = ((u32)a < (u32)N) && ((u32)b < (u32)N);
            int r  = ok ? cluster[a] : -1;
            int cc = ok ? cluster[b] : -1;
            bool m = (r >= 0) && (cc >= 0);
            mfl = m ? 1 : 0;
            __builtin_nontemporal_store(m ? (float)r  : 0.0f, o_ei + e);
            __builtin_nontemporal_store(m ? (float)cc : 0.0f, o_ei + (size_t)E + e);
            __builtin_nontemporal_store(m ? elen[e] : 0.0f, o_len + e);
            __builtin_nontemporal_store(m ? 1.0f : 0.0f, o_mask + e);
        }
        long long base4 = (long long)ch * 256;
        #pragma unroll
        for (int j = 0; j < 4; ++j) {
            long long idx4 = base4 + j * 64 + lane;
            int owner = j * 16 + (lane >> 2);
            int m = __shfl(mfl, owner);
            int ee = ch * 64 + owner;
            if (ee < E) {
                f32x4 v = {0.f, 0.f, 0.f, 0.f};
                if (m) v = attr4[idx4];
                __builtin_nontemporal_store(v, o_attr4 + idx4);
            }
        }
    }
}

extern "C" void kernel_launch(void* const* d_in, const int* in_sizes, int n_in,
                              void* d_out, int out_size, void* d_ws, size_t ws_size,
                              hipStream_t stream) {
    const float* x     = (const float*)d_in[0];
    const float* score = (const float*)d_in[1];
    const int*   ei    = (const int*)d_in[2];
    const float* eattr = (const float*)d_in[3];
    const int*   ntype = (const int*)d_in[4];
    const float* elen  = (const float*)d_in[5];

    const int N  = in_sizes[1];
    const int D  = in_sizes[0] / N;
    const int E  = in_sizes[5];
    const int DE = in_sizes[3] / E;
    const int k  = (N + 1) / 2;     // ceil(0.5 * N)

    // d_out is FLOAT32. RETURN-ORDER layout:
    // x_p | edge_index | edge_attr_p | node_type | perm | vals | edge_lengths | edge_mask
    float* out = (float*)d_out;
    const size_t o_xp    = 0;
    const size_t o_ei    = o_xp    + (size_t)k * D;
    const size_t o_eattr = o_ei    + 2 * (size_t)E;
    const size_t o_nt    = o_eattr + (size_t)E * DE;
    const size_t o_perm  = o_nt    + (size_t)k;
    const size_t o_vals  = o_perm  + (size_t)k;
    const size_t o_elen  = o_vals  + (size_t)k;
    const size_t o_emask = o_elen  + (size_t)E;

    const int nT = (N + TILE - 1) / TILE;              // 98
    const int histN = NDIG * nT;                       // 200704
    const int nChunk = histN / 256;                    // 784 (exact)

    char* ws = (char*)d_ws;
    u64* pack0   = (u64*)ws;     ws += 8 * (size_t)N;
    u64* pack1   = (u64*)ws;     ws += 8 * (size_t)N;
    u64* pay64   = (u64*)ws;     ws += 8 * (size_t)N;
    u32* hist_dt = (u32*)ws;     ws += 4 * (size_t)histN;
    u32* part    = (u32*)ws;     ws += 4 * (size_t)nChunk;
    u32* flags   = (u32*)ws;     ws += 4 * 2;
    int* cluster = (int*)ws;     ws += 4 * (size_t)N;

    const int nbN = (N + 255) / 256;

    // MSD pass on bits [21,32)
    k_countP<<<nT, 256, 0, stream>>>(score, pack0, cluster, ei, ntype, flags,
                                     hist_dt, N, nT);
    k_red<<<nChunk, 256, 0, stream>>>(hist_dt, part);
    k_scn<<<nChunk, 256, 0, stream>>>(hist_dt, part);
    k_scatR<<<nT, 256, 0, stream>>>(pack0, pack1, hist_dt, N, nT);
    // bucket-local LSD on bits [10,21): pack1 -> pack0
    k_lsort<<<NDIG, 256, 0, stream>>>(pack1, pack0, hist_dt, N, nT);
    // pack0 sorted by key bits [10,32), stable (idx-ascending within equal)

    k_pfix<<<nbN, 256, 0, stream>>>(pack0, pay64, cluster, ntype, &flags[1],
                                    out + o_nt, out + o_perm, out + o_vals, k, N);

    const int Dv = D / 4;
    const int gx = k * Dv;
    k_gx<<<(gx + 255) / 256, 256, 0, stream>>>(pay64, (const f32x4*)x,
                                               (f32x4*)(out + o_xp), k, Dv, N);
    k_ea<<<2048, 256, 0, stream>>>(ei, &flags[0], elen, cluster,
                                   (const f32x4*)eattr,
                                   out + o_ei, out + o_elen, out + o_emask,
                                   (f32x4*)(out + o_eattr), E, N);
}

// Round 26
// 138.811 us; speedup vs baseline: 100.0264x; 100.0264x over previous
//
#include <hip/hip_runtime.h>
#include <math.h>

typedef unsigned int u32;
typedef unsigned long long u64;
typedef float f32x4 __attribute__((ext_vector_type(4)));

#define NDIG1 4096         // 12-bit MSD digit: key bits [20,32)
#define SH1 20
#define NDIG2 1024         // 10-bit local digit: key bits [10,20)
#define SH2 10
#define TILE 1024          // elements per tile (pass-1 count/scatter)
#define CAP 6144           // max bucket len for LDS sort (worst ~4110+-65: 31 sigma)

// ===== Bit-exact replica of XLA's f32 tanh =====
__device__ __forceinline__ float xla_tanhf(float x) {
    float xc = fminf(fmaxf(x, -9.0f), 9.0f);
    float x2 = __fmul_rn(xc, xc);
    float p = -2.76076847742355e-16f;
    p = __fadd_rn(__fmul_rn(p, x2),  2.00018790482477e-13f);
    p = __fadd_rn(__fmul_rn(p, x2), -8.60467152213735e-11f);
    p = __fadd_rn(__fmul_rn(p, x2),  5.12229709037114e-08f);
    p = __fadd_rn(__fmul_rn(p, x2),  1.48572235717979e-05f);
    p = __fadd_rn(__fmul_rn(p, x2),  6.37261928875436e-04f);
    p = __fadd_rn(__fmul_rn(p, x2),  4.89352455891786e-03f);
    p = __fmul_rn(xc, p);
    float q = 1.19825839466702e-06f;
    q = __fadd_rn(__fmul_rn(q, x2),  1.18534705686654e-04f);
    q = __fadd_rn(__fmul_rn(q, x2),  2.26843463243900e-03f);
    q = __fadd_rn(__fmul_rn(q, x2),  4.89352518554385e-03f);
    float r = p / q;                     // IEEE f32 divide
    return (fabsf(x) < 0.0004f) ? x : r;
}

// ascending u32 order of key_desc(f) == DESCENDING float order of f (bijective)
__device__ __forceinline__ u32 key_desc(float f) {
    u32 u = __float_as_uint(f);
    u = (u & 0x80000000u) ? ~u : (u | 0x80000000u);
    return ~u;
}

// prep (tanh+pack+cluster) + LDS-atomic count of MSD digit + detect. 256 thr.
__global__ void k_countP(const float* __restrict__ score, u64* __restrict__ pack0,
                         int* __restrict__ cluster,
                         const int* __restrict__ ei, const int* __restrict__ ntype,
                         u32* __restrict__ flags, u32* __restrict__ hist_dt,
                         int N, int nT) {
    __shared__ u32 run[NDIG1];
    const int tile = blockIdx.x;
    const int tid = threadIdx.x;
    if (tile == 0 && tid < 64) {
        u64 b1 = __ballot(ei[2 * tid + 1] != 0);      // odd words 0 <=> int64 LE
        u64 b2 = __ballot(ntype[2 * tid + 1] != 0);
        if (tid == 0) { flags[0] = (b1 != 0ull) ? 1u : 0u;
                        flags[1] = (b2 != 0ull) ? 1u : 0u; }
    }
    for (int r = tid; r < NDIG1; r += 256) run[r] = 0u;
    __syncthreads();
    const int base = tile * TILE;
    #pragma unroll
    for (int j = 0; j < 4; ++j) {
        int e = base + j * 256 + tid;
        if (e < N) {
            float t = xla_tanhf(score[e]);
            cluster[e] = -1;
            u32 key = key_desc(t);
            pack0[e] = ((u64)key << 32) | (u32)e;
            atomicAdd(&run[(key >> SH1) & (NDIG1 - 1)], 1u);
        }
    }
    __syncthreads();
    for (int r = tid; r < NDIG1; r += 256)
        hist_dt[(size_t)r * nT + tile] = run[r];       // digit-major
}

// reduce 256-entry chunks -> part[]   (proven)
__global__ void k_red(const u32* __restrict__ h, u32* __restrict__ part) {
    __shared__ u32 sh[256];
    int b = blockIdx.x, t = threadIdx.x;
    sh[t] = h[(size_t)b * 256 + t];
    __syncthreads();
    for (int off = 128; off > 0; off >>= 1) {
        if (t < off) sh[t] += sh[t + off];
        __syncthreads();
    }
    if (t == 0) part[b] = sh[0];
}

// per-chunk: base = sum(part[0..b)) strided, chunk exclusive scan IN PLACE (proven)
__global__ void k_scn(u32* __restrict__ h, const u32* __restrict__ part) {
    __shared__ u32 sh[256];
    __shared__ u32 base_sh;
    int b = blockIdx.x, t = threadIdx.x;
    u32 acc = 0;
    for (int j = t; j < b; j += 256) acc += part[j];
    sh[t] = acc;
    __syncthreads();
    for (int off = 128; off > 0; off >>= 1) {
        if (t < off) sh[t] += sh[t + off];
        __syncthreads();
    }
    if (t == 0) base_sh = sh[0];
    __syncthreads();
    u32 base = base_sh;
    u32 v = h[(size_t)b * 256 + t];
    sh[t] = v;
    __syncthreads();
    for (int off = 1; off < 256; off <<= 1) {
        u32 x = sh[t];
        u32 y = (t >= off) ? sh[t - off] : 0u;
        __syncthreads();
        sh[t] = x + y;
        __syncthreads();
    }
    h[(size_t)b * 256 + t] = base + sh[t] - v;   // exclusive prefix
}

// stable MSD scatter; 2 waves/block (wcur 32KB), wave-chunk stable ranks
__global__ void k_scatR(const u64* __restrict__ src, u64* __restrict__ dst,
                        const u32* __restrict__ scn, int N, int nT) {
    __shared__ u32 wcur[2][NDIG1];
    const int tile = blockIdx.x;
    const int tid = threadIdx.x;       // 128 threads
    const int w = tid >> 6;
    const int lane = tid & 63;
    for (int r = tid; r < 2 * NDIG1; r += 128) ((u32*)wcur)[r] = 0u;
    __syncthreads();
    const int base = tile * TILE + w * 512;
    // (1) per-wave counts
    #pragma unroll
    for (int j = 0; j < 8; ++j) {
        int e = base + j * 64 + lane;
        if (e < N) {
            u32 key = (u32)(src[e] >> 32);
            atomicAdd(&wcur[w][(key >> SH1) & (NDIG1 - 1)], 1u);
        }
    }
    __syncthreads();
    // (2) exclusive prefix across the 2 waves per digit
    for (int r = tid; r < NDIG1; r += 128) {
        u32 a0 = wcur[0][r];
        wcur[0][r] = 0u;
        wcur[1][r] = a0;
    }
    __syncthreads();
    // (3) stable ballot scatter (wcur advances per round)
    #pragma unroll
    for (int j = 0; j < 8; ++j) {
        int e = base + j * 64 + lane;
        if (e < N) {
            u64 v = src[e];
            u32 key = (u32)(v >> 32);
            u32 d = (key >> SH1) & (NDIG1 - 1);
            u64 m = __ballot(1);
            for (int b = 0; b < 12; ++b) {
                u64 bb = __ballot((d >> b) & 1);
                m &= ((d >> b) & 1) ? bb : ~bb;
            }
            u32 wrank = (u32)__popcll(m & ((1ull << lane) - 1ull));
            u32 old = wcur[w][d];
            u32 pos = scn[(size_t)d * nT + tile] + old + wrank;
            int leader = __ffsll(m) - 1;
            if (lane == leader) wcur[w][d] = old + (u32)__popcll(m);
            if (pos < (u32)N) dst[pos] = v;
        }
    }
}

// bucket-local sort on key bits [10,20): one block per MSD bucket, in LDS.
// BOTH paths correctness-validated on-device in R25.
__global__ void k_lsort(const u64* __restrict__ src, u64* __restrict__ dst,
                        const u32* __restrict__ scn, int N, int nT) {
    __shared__ u64 el[CAP];
    __shared__ u32 cnt[NDIG2];
    __shared__ u32 sm[256];
    const int d = blockIdx.x;
    const int tid = threadIdx.x;
    const u32 lo = scn[(size_t)d * nT];
    const u32 hi = (d < NDIG1 - 1) ? scn[(size_t)(d + 1) * nT] : (u32)N;
    const int len = (int)(hi - lo);
    if (len <= 0) return;
    if (len <= CAP) {
        for (int i = tid; i < len; i += 256) el[i] = src[lo + i];
        for (int r = tid; r < NDIG2; r += 256) cnt[r] = 0u;
        __syncthreads();
        for (int i = tid; i < len; i += 256) {
            u32 d2 = ((u32)(el[i] >> 32) >> SH2) & (NDIG2 - 1);
            atomicAdd(&cnt[d2], 1u);
        }
        __syncthreads();
        // block exclusive scan of cnt[1024]: 4 per thread
        u32 s = 0;
        #pragma unroll
        for (int j = 0; j < 4; ++j) s += cnt[4 * tid + j];
        sm[tid] = s;
        __syncthreads();
        for (int off = 1; off < 256; off <<= 1) {
            u32 x = sm[tid];
            u32 y = (tid >= off) ? sm[tid - off] : 0u;
            __syncthreads();
            sm[tid] = x + y;
            __syncthreads();
        }
        u32 runv = sm[tid] - s;
        #pragma unroll
        for (int j = 0; j < 4; ++j) {
            u32 c = cnt[4 * tid + j];
            cnt[4 * tid + j] = runv;
            runv += c;
        }
        __syncthreads();
        // wave-0 sequential stable scatter (cursors in cnt[])
        if (tid < 64) {
            const int lane = tid;
            for (int base = 0; base < len; base += 64) {
                int e = base + lane;
                u32 d2 = 0; u64 v = 0;
                bool act = e < len;
                if (act) {
                    v = el[e];
                    d2 = ((u32)(v >> 32) >> SH2) & (NDIG2 - 1);
                }
                u64 am = __ballot(act);
                u64 m = am;
                for (int b = 0; b < 10; ++b) {
                    u64 bb = __ballot((d2 >> b) & 1);
                    m &= ((d2 >> b) & 1) ? bb : ~bb;
                }
                if (act) {
                    u32 wrank = (u32)__popcll(m & ((1ull << lane) - 1ull));
                    u32 old = cnt[d2];
                    u32 pos = old + wrank;
                    int leader = __ffsll(m & am) - 1;
                    if (lane == leader) cnt[d2] = old + (u32)__popcll(m & am);
                    if (pos < (u32)len) dst[lo + pos] = v;
                }
            }
        }
    } else {
        // slow path (31-sigma unreachable): exact rank brute force, correct
        for (int i = tid; i < len; i += 256) {
            u64 pk = src[lo + i];
            u32 rank = 0;
            for (int j = 0; j < len; ++j) rank += (src[lo + j] < pk);
            if (rank < (u32)len) dst[lo + rank] = pk;
        }
    }
}

// fix low-10-bit/idx order within same-top22 runs (tiny) + emit perm outputs
__global__ void k_pfix(const u64* __restrict__ srt, u64* __restrict__ pay64,
                       int* __restrict__ cluster,
                       const int* __restrict__ ntype, const u32* __restrict__ ntFlag,
                       float* __restrict__ o_nt, float* __restrict__ o_perm,
                       float* __restrict__ o_vals, int k, int N) {
    int r = blockIdx.x * blockDim.x + threadIdx.x;
    if (r >= N) return;
    u64 pk = srt[r];
    u64 t22 = pk >> 42;                  // sorted bits [10,32)
    int rs = r;
    while (rs > 0 && (r - rs) < 4096 && (srt[rs - 1] >> 42) == t22) --rs;
    int rf = rs;
    for (int j = rs; j < N && (j - rs) < 8192; ++j) {
        u64 q = srt[j];
        if ((q >> 42) != t22) break;
        rf += (q < pk);                  // full (key,idx) lexicographic order
    }
    if (rf < k) {
        u32 ip = (u32)pk;
        if (ip >= (u32)N) ip = 0;        // defensive
        u32 kb = (u32)(pk >> 32);
        u32 up = ~kb;                    // invert key_desc: recover tanh bits exactly
        u32 tb = (up >> 31) ? (up & 0x7FFFFFFFu) : ~up;
        pay64[rf] = ((u64)tb << 32) | ip;
        cluster[ip] = rf;
        o_perm[rf] = (float)ip;
        o_vals[rf] = __uint_as_float(tb);
        int nt = (*ntFlag == 0u) ? ntype[2 * (size_t)ip] : ntype[ip];
        o_nt[rf] = (float)nt;
    }
}

// x-gather: (val,idx) packed in pay64; regular loads, NT store
__global__ void k_gx(const u64* __restrict__ pay64,
                     const f32x4* __restrict__ x4, f32x4* __restrict__ out4,
                     int k, int Dv, int N) {
    int idx = blockIdx.x * blockDim.x + threadIdx.x;
    if (idx < k * Dv) {
        int r = idx / Dv, c = idx - r * Dv;
        u64 pv = pay64[r];
        u32 p = (u32)pv;
        float v = __uint_as_float((u32)(pv >> 32));
        if (p >= (u32)N) { p = 0; v = 0.0f; }   // defensive
        f32x4 a = x4[(size_t)p * Dv + c];
        a = a * v;
        __builtin_nontemporal_store(a, out4 + idx);
    }
}

// WAVE-chunked fused edges+attr (R16-proven)
__global__ void k_ea(const int* __restrict__ ei, const u32* __restrict__ eiFlag,
                     const float* __restrict__ elen, const int* __restrict__ cluster,
                     const f32x4* __restrict__ attr4,
                     float* __restrict__ o_ei, float* __restrict__ o_len,
                     float* __restrict__ o_mask, f32x4* __restrict__ o_attr4,
                     int E, int N) {
    const bool w64 = (*eiFlag == 0u);
    const int lane = threadIdx.x & 63;
    const int waveId = (blockIdx.x * blockDim.x + threadIdx.x) >> 6;
    const int nWaves = (gridDim.x * blockDim.x) >> 6;
    const int nChunk = (E + 63) >> 6;
    for (int ch = waveId; ch < nChunk; ch += nWaves) {
        int e = ch * 64 + lane;
        int mfl = 0;
        if (e < E) {
            int a, b;
            if (w64) { a = ei[2 * (size_t)e]; b = ei[2 * ((size_t)E + (size_t)e)]; }
            else { a = ei[e]; b = ei[(size_t)E + e]; }
            bool ok = ((u32)a < (u32)N) && ((u32)b < (u32)N);
            int r  = ok ? cluster[a] : -1;
            int cc = ok ? cluster[b] : -1;
            bool m = (r >= 0) && (cc >= 0);
            mfl = m ? 1 : 0;
            __builtin_nontemporal_store(m ? (float)r  : 0.0f, o_ei + e);
            __builtin_nontemporal_store(m ? (float)cc : 0.0f, o_ei + (size_t)E + e);
            __builtin_nontemporal_store(m ? elen[e] : 0.0f, o_len + e);
            __builtin_nontemporal_store(m ? 1.0f : 0.0f, o_mask + e);
        }
        long long base4 = (long long)ch * 256;
        #pragma unroll
        for (int j = 0; j < 4; ++j) {
            long long idx4 = base4 + j * 64 + lane;
            int owner = j * 16 + (lane >> 2);
            int m = __shfl(mfl, owner);
            int ee = ch * 64 + owner;
            if (ee < E) {
                f32x4 v = {0.f, 0.f, 0.f, 0.f};
                if (m) v = attr4[idx4];
                __builtin_nontemporal_store(v, o_attr4 + idx4);
            }
        }
    }
}

extern "C" void kernel_launch(void* const* d_in, const int* in_sizes, int n_in,
                              void* d_out, int out_size, void* d_ws, size_t ws_size,
                              hipStream_t stream) {
    const float* x     = (const float*)d_in[0];
    const float* score = (const float*)d_in[1];
    const int*   ei    = (const int*)d_in[2];
    const float* eattr = (const float*)d_in[3];
    const int*   ntype = (const int*)d_in[4];
    const float* elen  = (const float*)d_in[5];

    const int N  = in_sizes[1];
    const int D  = in_sizes[0] / N;
    const int E  = in_sizes[5];
    const int DE = in_sizes[3] / E;
    const int k  = (N + 1) / 2;     // ceil(0.5 * N)

    // d_out is FLOAT32. RETURN-ORDER layout:
    // x_p | edge_index | edge_attr_p | node_type | perm | vals | edge_lengths | edge_mask
    float* out = (float*)d_out;
    const size_t o_xp    = 0;
    const size_t o_ei    = o_xp    + (size_t)k * D;
    const size_t o_eattr = o_ei    + 2 * (size_t)E;
    const size_t o_nt    = o_eattr + (size_t)E * DE;
    const size_t o_perm  = o_nt    + (size_t)k;
    const size_t o_vals  = o_perm  + (size_t)k;
    const size_t o_elen  = o_vals  + (size_t)k;
    const size_t o_emask = o_elen  + (size_t)E;

    const int nT = (N + TILE - 1) / TILE;              // 98
    const int histN = NDIG1 * nT;                      // 401408
    const int nChunk = histN / 256;                    // 1568 (exact)

    char* ws = (char*)d_ws;
    u64* pack0   = (u64*)ws;     ws += 8 * (size_t)N;
    u64* pack1   = (u64*)ws;     ws += 8 * (size_t)N;
    u64* pay64   = (u64*)ws;     ws += 8 * (size_t)N;
    u32* hist_dt = (u32*)ws;     ws += 4 * (size_t)histN;
    u32* part    = (u32*)ws;     ws += 4 * (size_t)nChunk;
    u32* flags   = (u32*)ws;     ws += 4 * 2;
    int* cluster = (int*)ws;     ws += 4 * (size_t)N;

    const int nbN = (N + 255) / 256;

    // MSD pass on bits [20,32)
    k_countP<<<nT, 256, 0, stream>>>(score, pack0, cluster, ei, ntype, flags,
                                     hist_dt, N, nT);
    k_red<<<nChunk, 256, 0, stream>>>(hist_dt, part);
    k_scn<<<nChunk, 256, 0, stream>>>(hist_dt, part);
    k_scatR<<<nT, 128, 0, stream>>>(pack0, pack1, hist_dt, N, nT);
    // bucket-local sort on bits [10,20): pack1 -> pack0
    k_lsort<<<NDIG1, 256, 0, stream>>>(pack1, pack0, hist_dt, N, nT);
    // pack0 sorted by key bits [10,32), stable (idx-ascending within equal)

    k_pfix<<<nbN, 256, 0, stream>>>(pack0, pay64, cluster, ntype, &flags[1],
                                    out + o_nt, out + o_perm, out + o_vals, k, N);

    const int Dv = D / 4;
    const int gx = k * Dv;
    k_gx<<<(gx + 255) / 256, 256, 0, stream>>>(pay64, (const f32x4*)x,
                                               (f32x4*)(out + o_xp), k, Dv, N);
    k_ea<<<2048, 256, 0, stream>>>(ei, &flags[0], elen, cluster,
                                   (const f32x4*)eattr,
                                   out + o_ei, out + o_elen, out + o_emask,
                                   (f32x4*)(out + o_eattr), E, N);
}

// Round 27
// 114.777 us; speedup vs baseline: 120.9723x; 1.2094x over previous
//
#include <hip/hip_runtime.h>
#include <math.h>

typedef unsigned int u32;
typedef unsigned long long u64;
typedef float f32x4 __attribute__((ext_vector_type(4)));

#define NDIG 2048          // 11-bit digits
#define TILE 1024          // elements per tile (4 waves x 256)
#define NW 4               // waves per block

// ===== Bit-exact replica of XLA's f32 tanh =====
__device__ __forceinline__ float xla_tanhf(float x) {
    float xc = fminf(fmaxf(x, -9.0f), 9.0f);
    float x2 = __fmul_rn(xc, xc);
    float p = -2.76076847742355e-16f;
    p = __fadd_rn(__fmul_rn(p, x2),  2.00018790482477e-13f);
    p = __fadd_rn(__fmul_rn(p, x2), -8.60467152213735e-11f);
    p = __fadd_rn(__fmul_rn(p, x2),  5.12229709037114e-08f);
    p = __fadd_rn(__fmul_rn(p, x2),  1.48572235717979e-05f);
    p = __fadd_rn(__fmul_rn(p, x2),  6.37261928875436e-04f);
    p = __fadd_rn(__fmul_rn(p, x2),  4.89352455891786e-03f);
    p = __fmul_rn(xc, p);
    float q = 1.19825839466702e-06f;
    q = __fadd_rn(__fmul_rn(q, x2),  1.18534705686654e-04f);
    q = __fadd_rn(__fmul_rn(q, x2),  2.26843463243900e-03f);
    q = __fadd_rn(__fmul_rn(q, x2),  4.89352518554385e-03f);
    float r = p / q;                     // IEEE f32 divide
    return (fabsf(x) < 0.0004f) ? x : r;
}

// ascending u32 order of key_desc(f) == DESCENDING float order of f (bijective)
__device__ __forceinline__ u32 key_desc(float f) {
    u32 u = __float_as_uint(f);
    u = (u & 0x80000000u) ? ~u : (u | 0x80000000u);
    return ~u;
}

// prep (tanh+pack+cluster) + LDS-atomic count (pass A digits) + detect. 256 thr.
__global__ void k_countP(const float* __restrict__ score, u64* __restrict__ pack0,
                         int* __restrict__ cluster,
                         const int* __restrict__ ei, const int* __restrict__ ntype,
                         u32* __restrict__ flags, u32* __restrict__ hist_dt,
                         int N, int nT) {
    __shared__ u32 run[NDIG];
    const int tile = blockIdx.x;
    const int tid = threadIdx.x;
    if (tile == 0 && tid < 64) {
        u64 b1 = __ballot(ei[2 * tid + 1] != 0);      // odd words 0 <=> int64 LE
        u64 b2 = __ballot(ntype[2 * tid + 1] != 0);
        if (tid == 0) { flags[0] = (b1 != 0ull) ? 1u : 0u;
                        flags[1] = (b2 != 0ull) ? 1u : 0u; }
    }
    for (int r = tid; r < NDIG; r += 256) run[r] = 0u;
    __syncthreads();
    const int base = tile * TILE;
    #pragma unroll
    for (int j = 0; j < 4; ++j) {
        int e = base + j * 256 + tid;
        if (e < N) {
            float t = xla_tanhf(score[e]);
            cluster[e] = -1;
            u32 key = key_desc(t);
            pack0[e] = ((u64)key << 32) | (u32)e;
            atomicAdd(&run[(key >> 10) & (NDIG - 1)], 1u);
        }
    }
    __syncthreads();
    for (int r = tid; r < NDIG; r += 256)
        hist_dt[(size_t)r * nT + tile] = run[r];       // digit-major
}

// pass-B count: LDS-atomic, 256 thr
__global__ void k_count(const u64* __restrict__ src, u32* __restrict__ hist_dt,
                        int shift, int N, int nT) {
    __shared__ u32 run[NDIG];
    const int tile = blockIdx.x;
    const int tid = threadIdx.x;
    for (int r = tid; r < NDIG; r += 256) run[r] = 0u;
    __syncthreads();
    const int base = tile * TILE;
    #pragma unroll
    for (int j = 0; j < 4; ++j) {
        int e = base + j * 256 + tid;
        if (e < N) {
            u32 key = (u32)(src[e] >> 32);
            atomicAdd(&run[(key >> shift) & (NDIG - 1)], 1u);
        }
    }
    __syncthreads();
    for (int r = tid; r < NDIG; r += 256)
        hist_dt[(size_t)r * nT + tile] = run[r];
}

// reduce 256-entry chunks -> part[]   (proven)
__global__ void k_red(const u32* __restrict__ h, u32* __restrict__ part) {
    __shared__ u32 sh[256];
    int b = blockIdx.x, t = threadIdx.x;
    sh[t] = h[(size_t)b * 256 + t];
    __syncthreads();
    for (int off = 128; off > 0; off >>= 1) {
        if (t < off) sh[t] += sh[t + off];
        __syncthreads();
    }
    if (t == 0) part[b] = sh[0];
}

// per-chunk: base = sum(part[0..b)) strided, chunk exclusive scan IN PLACE (proven)
__global__ void k_scn(u32* __restrict__ h, const u32* __restrict__ part) {
    __shared__ u32 sh[256];
    __shared__ u32 base_sh;
    int b = blockIdx.x, t = threadIdx.x;
    u32 acc = 0;
    for (int j = t; j < b; j += 256) acc += part[j];
    sh[t] = acc;
    __syncthreads();
    for (int off = 128; off > 0; off >>= 1) {
        if (t < off) sh[t] += sh[t + off];
        __syncthreads();
    }
    if (t == 0) base_sh = sh[0];
    __syncthreads();
    u32 base = base_sh;
    u32 v = h[(size_t)b * 256 + t];
    sh[t] = v;
    __syncthreads();
    for (int off = 1; off < 256; off <<= 1) {
        u32 x = sh[t];
        u32 y = (t >= off) ? sh[t - off] : 0u;
        __syncthreads();
        sh[t] = x + y;
        __syncthreads();
    }
    h[(size_t)b * 256 + t] = base + sh[t] - v;   // exclusive prefix
}

// stable scatter, 4 waves/block. Wave w owns elements [base+w*256, +256) (index
// order). Phases: (1) per-wave LDS-atomic counts, (2) cross-wave exclusive
// prefix per digit, (3) per-round ballot scatter with wcur as pre-based cursor.
__global__ void k_scatR(const u64* __restrict__ src, u64* __restrict__ dst,
                        const u32* __restrict__ scn, int shift, int N, int nT) {
    __shared__ u32 wcur[NW][NDIG];
    const int tile = blockIdx.x;
    const int tid = threadIdx.x;
    const int w = tid >> 6;
    const int lane = tid & 63;
    for (int r = tid; r < NW * NDIG; r += 256) ((u32*)wcur)[r] = 0u;
    __syncthreads();
    const int base = tile * TILE + w * 256;
    // (1) count
    #pragma unroll
    for (int j = 0; j < 4; ++j) {
        int e = base + j * 64 + lane;
        if (e < N) {
            u32 key = (u32)(src[e] >> 32);
            atomicAdd(&wcur[w][(key >> shift) & (NDIG - 1)], 1u);
        }
    }
    __syncthreads();
    // (2) exclusive prefix across waves per digit
    for (int r = tid; r < NDIG; r += 256) {
        u32 a0 = wcur[0][r], a1 = wcur[1][r], a2 = wcur[2][r];
        wcur[0][r] = 0u;
        wcur[1][r] = a0;
        wcur[2][r] = a0 + a1;
        wcur[3][r] = a0 + a1 + a2;
    }
    __syncthreads();
    // (3) stable scatter (ballot rank within round; wcur advances per round)
    #pragma unroll
    for (int j = 0; j < 4; ++j) {
        int e = base + j * 64 + lane;
        if (e < N) {
            u64 v = src[e];
            u32 key = (u32)(v >> 32);
            u32 d = (key >> shift) & (NDIG - 1);
            u64 m = __ballot(1);
            for (int b = 0; b < 11; ++b) {
                u64 bb = __ballot((d >> b) & 1);
                m &= ((d >> b) & 1) ? bb : ~bb;
            }
            u32 wrank = (u32)__popcll(m & ((1ull << lane) - 1ull));
            u32 old = wcur[w][d];
            u32 pos = scn[(size_t)d * nT + tile] + old + wrank;
            int leader = __ffsll(m) - 1;
            if (lane == leader) wcur[w][d] = old + (u32)__popcll(m);
            if (pos < (u32)N) dst[pos] = v;
        }
    }
}

// fix low-10-bit/idx order within same-top22 runs (tiny) + emit perm outputs
__global__ void k_pfix(const u64* __restrict__ srt, u64* __restrict__ pay64,
                       int* __restrict__ cluster,
                       const int* __restrict__ ntype, const u32* __restrict__ ntFlag,
                       float* __restrict__ o_nt, float* __restrict__ o_perm,
                       float* __restrict__ o_vals, int k, int N) {
    int r = blockIdx.x * blockDim.x + threadIdx.x;
    if (r >= N) return;
    u64 pk = srt[r];
    u64 t22 = pk >> 42;
    int rs = r;
    while (rs > 0 && (r - rs) < 4096 && (srt[rs - 1] >> 42) == t22) --rs;
    int rf = rs;
    for (int j = rs; j < N && (j - rs) < 8192; ++j) {
        u64 q = srt[j];
        if ((q >> 42) != t22) break;
        rf += (q < pk);                  // full (key,idx) lexicographic order
    }
    if (rf < k) {
        u32 ip = (u32)pk;
        if (ip >= (u32)N) ip = 0;        // defensive
        u32 kb = (u32)(pk >> 32);
        u32 up = ~kb;                    // invert key_desc: recover tanh bits exactly
        u32 tb = (up >> 31) ? (up & 0x7FFFFFFFu) : ~up;
        pay64[rf] = ((u64)tb << 32) | ip;
        cluster[ip] = rf;
        o_perm[rf] = (float)ip;
        o_vals[rf] = __uint_as_float(tb);
        int nt = (*ntFlag == 0u) ? ntype[2 * (size_t)ip] : ntype[ip];
        o_nt[rf] = (float)nt;
    }
}

// x-gather: (val,idx) packed in pay64; regular loads, NT store
__global__ void k_gx(const u64* __restrict__ pay64,
                     const f32x4* __restrict__ x4, f32x4* __restrict__ out4,
                     int k, int Dv, int N) {
    int idx = blockIdx.x * blockDim.x + threadIdx.x;
    if (idx < k * Dv) {
        int r = idx / Dv, c = idx - r * Dv;
        u64 pv = pay64[r];
        u32 p = (u32)pv;
        float v = __uint_as_float((u32)(pv >> 32));
        if (p >= (u32)N) { p = 0; v = 0.0f; }   // defensive
        f32x4 a = x4[(size_t)p * Dv + c];
        a = a * v;
        __builtin_nontemporal_store(a, out4 + idx);
    }
}

// WAVE-chunked fused edges+attr (R16-proven)
__global__ void k_ea(const int* __restrict__ ei, const u32* __restrict__ eiFlag,
                     const float* __restrict__ elen, const int* __restrict__ cluster,
                     const f32x4* __restrict__ attr4,
                     float* __restrict__ o_ei, float* __restrict__ o_len,
                     float* __restrict__ o_mask, f32x4* __restrict__ o_attr4,
                     int E, int N) {
    const bool w64 = (*eiFlag == 0u);
    const int lane = threadIdx.x & 63;
    const int waveId = (blockIdx.x * blockDim.x + threadIdx.x) >> 6;
    const int nWaves = (gridDim.x * blockDim.x) >> 6;
    const int nChunk = (E + 63) >> 6;
    for (int ch = waveId; ch < nChunk; ch += nWaves) {
        int e = ch * 64 + lane;
        int mfl = 0;
        if (e < E) {
            int a, b;
            if (w64) { a = ei[2 * (size_t)e]; b = ei[2 * ((size_t)E + (size_t)e)]; }
            else { a = ei[e]; b = ei[(size_t)E + e]; }
            bool ok = ((u32)a < (u32)N) && ((u32)b < (u32)N);
            int r  = ok ? cluster[a] : -1;
            int cc = ok ? cluster[b] : -1;
            bool m = (r >= 0) && (cc >= 0);
            mfl = m ? 1 : 0;
            __builtin_nontemporal_store(m ? (float)r  : 0.0f, o_ei + e);
            __builtin_nontemporal_store(m ? (float)cc : 0.0f, o_ei + (size_t)E + e);
            __builtin_nontemporal_store(m ? elen[e] : 0.0f, o_len + e);
            __builtin_nontemporal_store(m ? 1.0f : 0.0f, o_mask + e);
        }
        long long base4 = (long long)ch * 256;
        #pragma unroll
        for (int j = 0; j < 4; ++j) {
            long long idx4 = base4 + j * 64 + lane;
            int owner = j * 16 + (lane >> 2);
            int m = __shfl(mfl, owner);
            int ee = ch * 64 + owner;
            if (ee < E) {
                f32x4 v = {0.f, 0.f, 0.f, 0.f};
                if (m) v = attr4[idx4];
                __builtin_nontemporal_store(v, o_attr4 + idx4);
            }
        }
    }
}

extern "C" void kernel_launch(void* const* d_in, const int* in_sizes, int n_in,
                              void* d_out, int out_size, void* d_ws, size_t ws_size,
                              hipStream_t stream) {
    const float* x     = (const float*)d_in[0];
    const float* score = (const float*)d_in[1];
    const int*   ei    = (const int*)d_in[2];
    const float* eattr = (const float*)d_in[3];
    const int*   ntype = (const int*)d_in[4];
    const float* elen  = (const float*)d_in[5];

    const int N  = in_sizes[1];
    const int D  = in_sizes[0] / N;
    const int E  = in_sizes[5];
    const int DE = in_sizes[3] / E;
    const int k  = (N + 1) / 2;     // ceil(0.5 * N)

    // d_out is FLOAT32. RETURN-ORDER layout:
    // x_p | edge_index | edge_attr_p | node_type | perm | vals | edge_lengths | edge_mask
    float* out = (float*)d_out;
    const size_t o_xp    = 0;
    const size_t o_ei    = o_xp    + (size_t)k * D;
    const size_t o_eattr = o_ei    + 2 * (size_t)E;
    const size_t o_nt    = o_eattr + (size_t)E * DE;
    const size_t o_perm  = o_nt    + (size_t)k;
    const size_t o_vals  = o_perm  + (size_t)k;
    const size_t o_elen  = o_vals  + (size_t)k;
    const size_t o_emask = o_elen  + (size_t)E;

    const int nT = (N + TILE - 1) / TILE;              // 98
    const int histN = NDIG * nT;                       // 200704
    const int nChunk = histN / 256;                    // 784 (exact)

    char* ws = (char*)d_ws;
    u64* pack0   = (u64*)ws;     ws += 8 * (size_t)N;
    u64* pack1   = (u64*)ws;     ws += 8 * (size_t)N;
    u64* pay64   = (u64*)ws;     ws += 8 * (size_t)N;
    u32* hist_dt = (u32*)ws;     ws += 4 * (size_t)histN;
    u32* part    = (u32*)ws;     ws += 4 * (size_t)nChunk;
    u32* flags   = (u32*)ws;     ws += 4 * 2;
    int* cluster = (int*)ws;     ws += 4 * (size_t)N;

    const int nbN = (N + 255) / 256;

    // pass A: bits [10,21)
    k_countP<<<nT, 256, 0, stream>>>(score, pack0, cluster, ei, ntype, flags,
                                     hist_dt, N, nT);
    k_red<<<nChunk, 256, 0, stream>>>(hist_dt, part);
    k_scn<<<nChunk, 256, 0, stream>>>(hist_dt, part);
    k_scatR<<<nT, 256, 0, stream>>>(pack0, pack1, hist_dt, 10, N, nT);

    // pass B: bits [21,32)
    k_count<<<nT, 256, 0, stream>>>(pack1, hist_dt, 21, N, nT);
    k_red<<<nChunk, 256, 0, stream>>>(hist_dt, part);
    k_scn<<<nChunk, 256, 0, stream>>>(hist_dt, part);
    k_scatR<<<nT, 256, 0, stream>>>(pack1, pack0, hist_dt, 21, N, nT);
    // pack0 sorted by key bits [10,32), stable (idx-ascending within equal)

    k_pfix<<<nbN, 256, 0, stream>>>(pack0, pay64, cluster, ntype, &flags[1],
                                    out + o_nt, out + o_perm, out + o_vals, k, N);

    const int Dv = D / 4;
    const int gx = k * Dv;
    k_gx<<<(gx + 255) / 256, 256, 0, stream>>>(pay64, (const f32x4*)x,
                                               (f32x4*)(out + o_xp), k, Dv, N);
    k_ea<<<2048, 256, 0, stream>>>(ei, &flags[0], elen, cluster,
                                   (const f32x4*)eattr,
                                   out + o_ei, out + o_elen, out + o_emask,
                                   (f32x4*)(out + o_eattr), E, N);
}